// Round 3
// baseline (34952.951 us; speedup 1.0000x reference)
//
#include <hip/hip_runtime.h>
#include <math.h>

// ---------------------------------------------------------------------------
// VRNN on MI355X — round 3.
// Rounds 0/2 were barrier-bound: ~30µs per grid barrier, traced to the
// agent-scope __threadfence() in gridbar => buffer_wbl2+buffer_inv (full L2
// writeback+invalidate per XCD, 3x per barrier) since per-XCD L2s are not
// coherent. Round 3 removes ALL fences: every cross-WG datum is moved with
// relaxed agent-scope atomics (global_load/store sc0 sc1 -> coherent at L3),
// so no cache maintenance is ever needed. Weights stay in LDS (128KiB/WG,
// col-partitioned, staged once) + plain L2-cached read-only tables.
// Phases/step (4 grid barriers, was 5):
//   Ph1: A = relu(pre_enc + h@enc_w1_h)   [WG 0..15]  + GH = h@gru_hh+b [16..31]
//   Ph2: E = relu(A@enc_w2 + b2)          [WG 16..31]
//   Ph3: rows 16w: ems -> z -> out; pz    [WG 0..15]  (row-local, merged)
//   Ph4: gx = gx16 + pz@gru_ih_pz; GRU    [WG 0..15]
// GXPX = px@gru_w_ih[:512]+b_ih precomputed batched fp16.
// All GEMMs: bf16 MFMA 16x16x32, fp32 accum, weights pre-transposed to [N][K].
// ---------------------------------------------------------------------------

#define NWG 32
#define TT 200
#define BB 256
#define HD 512
#define TB (TT*BB)   // 51200

typedef unsigned short u16;
typedef unsigned long long u64;
typedef _Float16 f16;
typedef __attribute__((ext_vector_type(8))) short bf16x8;
typedef __attribute__((ext_vector_type(4))) float f32x4;

// output layout (fp32, concatenated flat): z, logits, em, es, pm, ps, kld
constexpr size_t OFF_Z      = 0;
constexpr size_t OFF_LOGITS = 3276800;
constexpr size_t OFF_EM     = 16384000;
constexpr size_t OFF_ES     = 19660800;
constexpr size_t OFF_PM     = 22937600;
constexpr size_t OFF_PS     = 26214400;
constexpr size_t OFF_KLD    = 29491200;

__device__ __forceinline__ u16 f2bf(float f) {
  union { float f; unsigned u; } v; v.f = f;
  return (u16)((v.u + 0x7fffu + ((v.u >> 16) & 1u)) >> 16);  // RNE
}
__device__ __forceinline__ float bf2f(u16 b) {
  union { unsigned u; float f; } v; v.u = ((unsigned)b) << 16; return v.f;
}
__device__ __forceinline__ float sp_(float x) { return (x > 15.f) ? x : log1pf(expf(x)); }
__device__ __forceinline__ float sigm_(float x) { return 1.f / (1.f + __expf(-x)); }
__device__ __forceinline__ float tanh_(float x) { return 1.f - 2.f / (1.f + __expf(2.f * x)); }

#define MFMA(a,b,c) __builtin_amdgcn_mfma_f32_16x16x32_bf16((a),(b),(c),0,0,0)

// --- coherent (L3-level, sc0 sc1) access helpers: no fences ever needed ---
union B8 { u64 q[2]; bf16x8 v; };
__device__ __forceinline__ bf16x8 ldc16(const u16* p) {     // 16B coherent load
  B8 b;
  b.q[0] = __hip_atomic_load((const u64*)p,     __ATOMIC_RELAXED, __HIP_MEMORY_SCOPE_AGENT);
  b.q[1] = __hip_atomic_load((const u64*)p + 1, __ATOMIC_RELAXED, __HIP_MEMORY_SCOPE_AGENT);
  return b.v;
}
__device__ __forceinline__ void stc2(u16* p, u16 a) {       // 2B coherent store
  __hip_atomic_store(p, a, __ATOMIC_RELAXED, __HIP_MEMORY_SCOPE_AGENT);
}
__device__ __forceinline__ void stc4f(float* p, float x) {  // 4B coherent store
  union { float f; unsigned u; } c; c.f = x;
  __hip_atomic_store((unsigned*)p, c.u, __ATOMIC_RELAXED, __HIP_MEMORY_SCOPE_AGENT);
}
__device__ __forceinline__ float ldc4f(const float* p) {    // 4B coherent load
  unsigned u = __hip_atomic_load((const unsigned*)p, __ATOMIC_RELAXED, __HIP_MEMORY_SCOPE_AGENT);
  union { unsigned u; float f; } c; c.u = u; return c.f;
}

// LDS XOR-swizzle for [row][512] bf16 weight slices (row stride 1024B).
#define SWZ(row, cb)  (((row) << 10) + ((cb) ^ (((row) & 7) << 4)))
// [16][64] bf16 tile, row stride 128B
#define SWZZ(row, cb) (((row) << 7)  + ((cb) ^ (((row) & 7) << 4)))

// ---------------------------------------------------------------------------
// weight cast+transpose: dst[c*R + r] = bf16(src[r*C + c])   (dst is [C][R])
// ---------------------------------------------------------------------------
#define NSEG 18
struct CastSeg { const float* src; u16* dst; int R; int C; };
struct CastArgs { CastSeg seg[NSEG]; };

__global__ __launch_bounds__(256) void cast_all(CastArgs a) {
  int idx = blockIdx.x * 256 + threadIdx.x;
  #pragma unroll 1
  for (int s = 0; s < NSEG; s++) {
    const int R = a.seg[s].R, C = a.seg[s].C;
    const int sz = R * C;
    if (idx < sz) {
      const int r = idx / C, c = idx - r * C;
      a.seg[s].dst[(size_t)c * R + r] = f2bf(a.seg[s].src[idx]);
      return;
    }
    idx -= sz;
  }
}

__global__ __launch_bounds__(256) void init_k(float* h_cur, u16* H0, unsigned* sync) {
  const int i = blockIdx.x * 256 + threadIdx.x;
  if (i < BB * HD) { h_cur[i] = 0.f; H0[i] = 0; }
  if (i < 2052) sync[i] = 0u;
}

// ---------------------------------------------------------------------------
// generic batched GEMM:  out = act( A1@Bt1^T [+ A2@Bt2^T] + bias )
// ---------------------------------------------------------------------------
struct GB {
  const void* A1; int lda1, K1, a1f32;
  const u16* Bt1;
  const u16* A2; int lda2, K2;
  const u16* Bt2;
  const float* bias;
  u16* outB; float* outF; f16* outH; int ldc;
  int tilesN; int act;   // act: 0 none, 1 relu
};

__device__ __forceinline__ bf16x8 load_a8(const void* A, int f32, size_t row, int lda, int k) {
  if (!f32) return *(const bf16x8*)((const u16*)A + row * (size_t)lda + k);
  const float* p = (const float*)A + row * (size_t)lda + k;
  f32x4 x0 = *(const f32x4*)p;
  f32x4 x1 = *(const f32x4*)(p + 4);
  bf16x8 r;
  r[0]=(short)f2bf(x0[0]); r[1]=(short)f2bf(x0[1]); r[2]=(short)f2bf(x0[2]); r[3]=(short)f2bf(x0[3]);
  r[4]=(short)f2bf(x1[0]); r[5]=(short)f2bf(x1[1]); r[6]=(short)f2bf(x1[2]); r[7]=(short)f2bf(x1[3]);
  return r;
}

__global__ __launch_bounds__(256) void gemm_bt(GB g) {
  const int tn = blockIdx.x % g.tilesN, tm = blockIdx.x / g.tilesN;
  const int m0 = tm * 64, n0 = tn * 64;
  const int v = threadIdx.x >> 6, l = threadIdx.x & 63, lm = l & 15, q = l >> 4;
  const size_t rowA = m0 + v * 16 + lm;
  f32x4 acc[4] = {};
  for (int k0 = 0; k0 < g.K1; k0 += 32) {
    bf16x8 a = load_a8(g.A1, g.a1f32, rowA, g.lda1, k0 + q * 8);
    #pragma unroll
    for (int c = 0; c < 4; c++) {
      bf16x8 b = *(const bf16x8*)(g.Bt1 + (size_t)(n0 + c * 16 + lm) * g.K1 + k0 + q * 8);
      acc[c] = MFMA(a, b, acc[c]);
    }
  }
  if (g.A2) {
    for (int k0 = 0; k0 < g.K2; k0 += 32) {
      bf16x8 a = *(const bf16x8*)(g.A2 + rowA * (size_t)g.lda2 + k0 + q * 8);
      #pragma unroll
      for (int c = 0; c < 4; c++) {
        bf16x8 b = *(const bf16x8*)(g.Bt2 + (size_t)(n0 + c * 16 + lm) * g.K2 + k0 + q * 8);
        acc[c] = MFMA(a, b, acc[c]);
      }
    }
  }
  #pragma unroll
  for (int c = 0; c < 4; c++) {
    const int col = n0 + c * 16 + lm;
    const float bs = g.bias ? g.bias[col] : 0.f;
    #pragma unroll
    for (int r = 0; r < 4; r++) {
      const size_t row = (size_t)m0 + v * 16 + q * 4 + r;
      float x = acc[c][r] + bs;
      if (g.act == 1) x = fmaxf(x, 0.f);
      if (g.outB) g.outB[row * g.ldc + col] = f2bf(x);
      if (g.outF) g.outF[row * g.ldc + col] = x;
      if (g.outH) g.outH[row * g.ldc + col] = (f16)x;
    }
  }
}

// ---------------------------------------------------------------------------
// prior mean/std heads + kld, fused (post-pass).
// ---------------------------------------------------------------------------
__global__ __launch_bounds__(256) void pms_kld(const u16* PR, const u16* pms_t,
                                               const float* pmb, const float* psb,
                                               float* out) {
  const int m0 = blockIdx.x * 64;
  const int v = threadIdx.x >> 6, l = threadIdx.x & 63, lm = l & 15, q = l >> 4;
  const size_t rowA = m0 + v * 16 + lm;
  f32x4 acc[8] = {};
  for (int k0 = 0; k0 < 512; k0 += 32) {
    bf16x8 a = *(const bf16x8*)(PR + rowA * 512 + k0 + q * 8);
    #pragma unroll
    for (int c = 0; c < 8; c++) {
      bf16x8 b = *(const bf16x8*)(pms_t + (size_t)(c * 16 + lm) * 512 + k0 + q * 8);
      acc[c] = MFMA(a, b, acc[c]);
    }
  }
  #pragma unroll
  for (int c = 0; c < 4; c++) {
    const int colz = c * 16 + lm;
    #pragma unroll
    for (int r = 0; r < 4; r++) {
      const size_t row = (size_t)m0 + v * 16 + q * 4 + r;
      const float pm = acc[c][r] + pmb[colz];
      const float ps = sp_(acc[c + 4][r] + psb[colz]);
      const size_t oi = row * 64 + colz;
      const float em = out[OFF_EM + oi], es = out[OFF_ES + oi];
      const float d = em - pm;
      const float kld = 0.5f * (2.f * logf(ps) - 2.f * logf(es)
                                + (es * es + d * d) / (ps * ps) - 1.f);
      out[OFF_PM + oi] = pm;
      out[OFF_PS + oi] = ps;
      out[OFF_KLD + oi] = kld;
    }
  }
}

// ---------------------------------------------------------------------------
// persistent scan kernel: 32 WGs, col-partitioned LDS weights, fence-free.
// ---------------------------------------------------------------------------
struct SC {
  const u16 *pre_enc;     // BUF0, [TT][256][512] bf16 (plain read in Ph1)
  u16 *pz_out;            // == BUF0 (slice t sc-overwritten with pz in Ph3)
  u16 *H;                 // [(TT+1)][256][512] bf16; sc r/w
  float *h_cur;           // [256][512] fp32 carry; plain, WG-col-local
  u16 *Abuf, *Ebuf;       // step scratch bf16 [256][512]; sc r/w
  float *GH;              // [256][1536] fp32 (h@gru_hh + b_hh); sc r/w
  const f16 *gx;          // [TB][1536] fp16: px@gru_w_ih[:512] + b_ih; plain
  const u16 *enc_w1_h_t, *enc_w2_t, *ems_t, *phi_z_t, *gru_hh_t, *gru_ih_pz_t;
  const float *enc_b2, *enc_mean_b, *enc_std_b, *phi_z_b, *gru_b_hh;
  const float *eps;
  float *out;
  unsigned *flags, *gen;
};

// Fence-free grid barrier. All cross-WG data moves via sc0sc1 (coherent)
// atomics, so no wbl2/inv is needed. __syncthreads() emits
// s_waitcnt vmcnt(0) before s_barrier => our write-through stores have
// reached the coherence point before the flag store issues.
__device__ __forceinline__ void gridbar(unsigned* flags, unsigned* gen, unsigned ticket) {
  __syncthreads();
  if (threadIdx.x == 0) {
    __hip_atomic_store(&flags[(size_t)blockIdx.x * 32], ticket,
                       __ATOMIC_RELAXED, __HIP_MEMORY_SCOPE_AGENT);
  }
  if (blockIdx.x == 0) {
    if (threadIdx.x < NWG) {
      while (__hip_atomic_load(&flags[(size_t)threadIdx.x * 32],
                               __ATOMIC_RELAXED, __HIP_MEMORY_SCOPE_AGENT) < ticket) {}
    }
    __syncthreads();
    if (threadIdx.x == 0) {
      __hip_atomic_store(gen, ticket, __ATOMIC_RELAXED, __HIP_MEMORY_SCOPE_AGENT);
    }
  }
  if (threadIdx.x == 0) {
    while (__hip_atomic_load(gen, __ATOMIC_RELAXED, __HIP_MEMORY_SCOPE_AGENT) < ticket) {
      __builtin_amdgcn_s_sleep(1);
    }
  }
  __syncthreads();
}

__global__ __launch_bounds__(256, 1) void scan_k(SC s) {
  const int w = blockIdx.x;
  const int tid = threadIdx.x;
  const int v = tid >> 6, l = tid & 63, lm = l & 15, q = l >> 4;

  // 128KiB weight slices, swizzled (same layout as round 2):
  //  w<16 : [0..32)=enc_w1_h cols[32w..); [32..128)=gru_ih_pz gate-triple
  //  w>=16: [0..96)=gru_hh gate-triple;   [96..128)=enc_w2 cols[32(w-16)..)
  __shared__ u16 wlds[65536];
  __shared__ float emsb[16 * 128];   // Ph3 scratch (w<16)
  __shared__ u16 zb[16 * 64];        // Ph3 scratch (w<16)

  {
    const int ww = (w < 16) ? w : w - 16;
    const u16* srcs[4];
    if (w < 16) {
      srcs[0] = s.enc_w1_h_t  + (size_t)(32 * ww) * 512;
      srcs[1] = s.gru_ih_pz_t + (size_t)(32 * ww) * 512;
      srcs[2] = s.gru_ih_pz_t + (size_t)(512 + 32 * ww) * 512;
      srcs[3] = s.gru_ih_pz_t + (size_t)(1024 + 32 * ww) * 512;
    } else {
      srcs[0] = s.gru_hh_t + (size_t)(32 * ww) * 512;
      srcs[1] = s.gru_hh_t + (size_t)(512 + 32 * ww) * 512;
      srcs[2] = s.gru_hh_t + (size_t)(1024 + 32 * ww) * 512;
      srcs[3] = s.enc_w2_t + (size_t)(32 * ww) * 512;
    }
    #pragma unroll 1
    for (int rg = 0; rg < 4; rg++) {
      const u16* sp = srcs[rg];
      const int r0 = rg * 32;
      for (int idx = tid; idx < 32 * 512; idx += 256) {
        const int lr = idx >> 9, k = idx & 511;
        *(u16*)((char*)wlds + SWZ(r0 + lr, k * 2)) = sp[(size_t)lr * 512 + k];
      }
    }
  }
  __syncthreads();

  #define LB(lr, kk) (*(const bf16x8*)((const char*)wlds + SWZ((lr), (kk) * 2)))

  #pragma unroll 1
  for (int t = 0; t < TT; t++) {
    // ===== Ph1: A [w<16] / GH [w>=16]; h read coherent =====
    {
      const u16* Ht = s.H + (size_t)t * (BB * HD);
      if (w < 16) {
        const u16* pre = s.pre_enc + (size_t)t * (BB * HD);
        u16 pr[2][4][4];
        #pragma unroll
        for (int ct = 0; ct < 2; ct++)
          #pragma unroll
          for (int rt = 0; rt < 4; rt++)
            #pragma unroll
            for (int r = 0; r < 4; r++)
              pr[ct][rt][r] = pre[(size_t)(v * 64 + rt * 16 + q * 4 + r) * 512
                                  + 32 * w + ct * 16 + lm];
        f32x4 acc[4][2] = {};
        for (int k0 = 0; k0 < 512; k0 += 32) {
          const bf16x8 b0 = LB(lm, k0 + q * 8);
          const bf16x8 b1 = LB(16 + lm, k0 + q * 8);
          #pragma unroll
          for (int rt = 0; rt < 4; rt++) {
            bf16x8 a = ldc16(Ht + (size_t)(v * 64 + rt * 16 + lm) * 512 + k0 + q * 8);
            acc[rt][0] = MFMA(a, b0, acc[rt][0]);
            acc[rt][1] = MFMA(a, b1, acc[rt][1]);
          }
        }
        #pragma unroll
        for (int ct = 0; ct < 2; ct++) {
          const int col = 32 * w + ct * 16 + lm;
          #pragma unroll
          for (int rt = 0; rt < 4; rt++)
            #pragma unroll
            for (int r = 0; r < 4; r++) {
              const int row = v * 64 + rt * 16 + q * 4 + r;
              const float x = acc[rt][ct][r] + bf2f(pr[ct][rt][r]);
              stc2(&s.Abuf[(size_t)row * 512 + col], f2bf(fmaxf(x, 0.f)));
            }
        }
      } else {
        const int ww = w - 16;
        float bs[6];
        #pragma unroll
        for (int g = 0; g < 3; g++)
          #pragma unroll
          for (int sub = 0; sub < 2; sub++)
            bs[g * 2 + sub] = s.gru_b_hh[g * 512 + 32 * ww + sub * 16 + lm];
        f32x4 acc[4][6] = {};
        for (int k0 = 0; k0 < 512; k0 += 32) {
          bf16x8 b[6];
          #pragma unroll
          for (int ctn = 0; ctn < 6; ctn++)
            b[ctn] = LB((ctn >> 1) * 32 + (ctn & 1) * 16 + lm, k0 + q * 8);
          #pragma unroll
          for (int rt = 0; rt < 4; rt++) {
            bf16x8 a = ldc16(Ht + (size_t)(v * 64 + rt * 16 + lm) * 512 + k0 + q * 8);
            #pragma unroll
            for (int ctn = 0; ctn < 6; ctn++)
              acc[rt][ctn] = MFMA(a, b[ctn], acc[rt][ctn]);
          }
        }
        #pragma unroll
        for (int ctn = 0; ctn < 6; ctn++) {
          const int col = (ctn >> 1) * 512 + 32 * ww + (ctn & 1) * 16 + lm;
          #pragma unroll
          for (int rt = 0; rt < 4; rt++)
            #pragma unroll
            for (int r = 0; r < 4; r++) {
              const int row = v * 64 + rt * 16 + q * 4 + r;
              stc4f(&s.GH[(size_t)row * 1536 + col], acc[rt][ctn][r] + bs[ctn]);
            }
        }
      }
    }
    gridbar(s.flags, s.gen, (unsigned)(t * 4 + 1));

    // ===== Ph2: E = relu(A@enc_w2 + b2) [w>=16] =====
    if (w >= 16) {
      const int ww = w - 16;
      f32x4 acc[4][2] = {};
      for (int k0 = 0; k0 < 512; k0 += 32) {
        const bf16x8 b0 = LB(96 + lm, k0 + q * 8);
        const bf16x8 b1 = LB(112 + lm, k0 + q * 8);
        #pragma unroll
        for (int rt = 0; rt < 4; rt++) {
          bf16x8 a = ldc16(s.Abuf + (size_t)(v * 64 + rt * 16 + lm) * 512 + k0 + q * 8);
          acc[rt][0] = MFMA(a, b0, acc[rt][0]);
          acc[rt][1] = MFMA(a, b1, acc[rt][1]);
        }
      }
      #pragma unroll
      for (int ct = 0; ct < 2; ct++) {
        const int col = 32 * ww + ct * 16 + lm;
        const float bsv = s.enc_b2[col];
        #pragma unroll
        for (int rt = 0; rt < 4; rt++)
          #pragma unroll
          for (int r = 0; r < 4; r++) {
            const int row = v * 64 + rt * 16 + q * 4 + r;
            stc2(&s.Ebuf[(size_t)row * 512 + col], f2bf(fmaxf(acc[rt][ct][r] + bsv, 0.f)));
          }
      }
    }
    gridbar(s.flags, s.gen, (unsigned)(t * 4 + 2));

    // ===== Ph3: rows 16w: ems -> z -> out; pz  [w<16, row-local] =====
    if (w < 16) {
      const int r0 = w * 16;
      {  // ems: wave v computes cols v*32..v*32+32 (of 128)
        f32x4 e0 = {}, e1 = {};
        const int cb = v * 32;
        for (int k0 = 0; k0 < 512; k0 += 32) {
          bf16x8 a  = ldc16(s.Ebuf + (size_t)(r0 + lm) * 512 + k0 + q * 8);
          bf16x8 b0 = *(const bf16x8*)(s.ems_t + (size_t)(cb + lm) * 512 + k0 + q * 8);
          bf16x8 b1 = *(const bf16x8*)(s.ems_t + (size_t)(cb + 16 + lm) * 512 + k0 + q * 8);
          e0 = MFMA(a, b0, e0);
          e1 = MFMA(a, b1, e1);
        }
        #pragma unroll
        for (int ct = 0; ct < 2; ct++) {
          const int col = cb + ct * 16 + lm;
          const float bsv = (col < 64) ? s.enc_mean_b[col] : s.enc_std_b[col - 64];
          const f32x4 ee = ct ? e1 : e0;
          #pragma unroll
          for (int r = 0; r < 4; r++)
            emsb[(q * 4 + r) * 128 + col] = ee[r] + bsv;
        }
      }
      __syncthreads();
      #pragma unroll
      for (int i = 0; i < 4; i++) {
        const int e = tid + i * 256;              // 16 rows x 64 cols
        const int rr = e >> 6, cc = e & 63;
        const float em = emsb[rr * 128 + cc];
        const float es = sp_(emsb[rr * 128 + 64 + cc]);
        const int row = r0 + rr;
        const size_t oi = ((size_t)t * BB + row) * 64 + cc;
        const float z = s.eps[oi] * es + em;
        s.out[OFF_Z + oi]  = z;
        s.out[OFF_EM + oi] = em;
        s.out[OFF_ES + oi] = es;
        *(u16*)((char*)zb + SWZZ(rr, cc * 2)) = f2bf(z);
      }
      __syncthreads();
      {  // pz rows r0..r0+16, all 512 cols; phi_z from global (L2-hot)
        u16* pzg = s.pz_out + (size_t)t * (BB * HD);
        #pragma unroll
        for (int ct = 0; ct < 8; ct++) {
          const int cz = v * 128 + ct * 16;
          f32x4 pa = {};
          #pragma unroll
          for (int k0 = 0; k0 < 64; k0 += 32) {
            bf16x8 a = *(const bf16x8*)((const char*)zb + SWZZ(lm, (k0 + q * 8) * 2));
            bf16x8 b = *(const bf16x8*)(s.phi_z_t + (size_t)(cz + lm) * 64 + k0 + q * 8);
            pa = MFMA(a, b, pa);
          }
          const int col = cz + lm;
          const float bsv = s.phi_z_b[col];
          #pragma unroll
          for (int r = 0; r < 4; r++) {
            const int row = r0 + q * 4 + r;
            stc2(&pzg[(size_t)row * 512 + col], f2bf(fmaxf(pa[r] + bsv, 0.f)));
          }
        }
      }
    }
    gridbar(s.flags, s.gen, (unsigned)(t * 4 + 3));

    // ===== Ph4: gx = gx16 + pz@gru_ih_pz; GRU update [w<16] =====
    if (w < 16) {
      const u16* pz = s.pz_out + (size_t)t * (BB * HD);
      f32x4 acc[4][6] = {};
      for (int k0 = 0; k0 < 512; k0 += 32) {
        bf16x8 b[6];
        #pragma unroll
        for (int ctn = 0; ctn < 6; ctn++)
          b[ctn] = LB(32 + (ctn >> 1) * 32 + (ctn & 1) * 16 + lm, k0 + q * 8);
        #pragma unroll
        for (int rt = 0; rt < 4; rt++) {
          bf16x8 a = ldc16(pz + (size_t)(v * 64 + rt * 16 + lm) * 512 + k0 + q * 8);
          #pragma unroll
          for (int ctn = 0; ctn < 6; ctn++)
            acc[rt][ctn] = MFMA(a, b[ctn], acc[rt][ctn]);
        }
      }
      const f16* gxt = s.gx + (size_t)t * BB * 1536;
      u16* Hn = s.H + (size_t)(t + 1) * (BB * HD);
      #pragma unroll
      for (int sub = 0; sub < 2; sub++) {
        const int j = 32 * w + sub * 16 + lm;
        #pragma unroll
        for (int rt = 0; rt < 4; rt++)
          #pragma unroll
          for (int r = 0; r < 4; r++) {
            const int row = v * 64 + rt * 16 + q * 4 + r;
            const size_t base = (size_t)row * 1536;
            const float xr = acc[rt][0 + sub][r] + (float)gxt[base + j];
            const float xz = acc[rt][2 + sub][r] + (float)gxt[base + 512 + j];
            const float xn = acc[rt][4 + sub][r] + (float)gxt[base + 1024 + j];
            const float hr = ldc4f(&s.GH[base + j]);
            const float hz = ldc4f(&s.GH[base + 512 + j]);
            const float hn = ldc4f(&s.GH[base + 1024 + j]);
            const float rg = sigm_(xr + hr);
            const float uu = sigm_(xz + hz);
            const float nn = tanh_(xn + rg * hn);
            const float hold = s.h_cur[(size_t)row * 512 + j];
            const float hnew = (1.f - uu) * nn + uu * hold;
            s.h_cur[(size_t)row * 512 + j] = hnew;
            stc2(&Hn[(size_t)row * 512 + j], f2bf(hnew));
          }
      }
    }
    gridbar(s.flags, s.gen, (unsigned)(t * 4 + 4));
  }
  #undef LB
}

// ---------------------------------------------------------------------------
extern "C" void kernel_launch(void* const* d_in, const int* in_sizes, int n_in,
                              void* d_out, int out_size, void* d_ws, size_t ws_size,
                              hipStream_t stream) {
  (void)in_sizes; (void)n_in; (void)out_size; (void)ws_size;
  char* ws = (char*)d_ws;
  float* out = (float*)d_out;
  auto in = [&](int i) { return (const float*)d_in[i]; };

  size_t o = 0;
  auto take = [&](size_t bytes) { size_t r = o; o += (bytes + 255) & ~(size_t)255; return r; };
  const size_t oPhiXW1  = take(512 * 128 * 2);
  const size_t oPhiXW2  = take(512 * 512 * 2);
  const size_t oEncW1px = take(512 * 512 * 2);
  const size_t oEncW1h  = take(512 * 512 * 2);
  const size_t oEncW2   = take(512 * 512 * 2);
  const size_t oEms     = take(128 * 512 * 2);
  const size_t oPhiZ    = take(512 * 64 * 2);
  const size_t oPriorW  = take(512 * 512 * 2);
  const size_t oPriorMs = take(128 * 512 * 2);
  const size_t oDecW1pz = take(512 * 512 * 2);
  const size_t oDecW1h  = take(512 * 512 * 2);
  const size_t oDecW2   = take(512 * 512 * 2);
  const size_t oDecLog  = take(256 * 512 * 2);
  const size_t oGruIhPx = take((size_t)1536 * 512 * 2);
  const size_t oGruIhPz = take((size_t)1536 * 512 * 2);
  const size_t oGruHh   = take((size_t)1536 * 512 * 2);
  const size_t oBuf0    = take((size_t)TB * 512 * 2);
  const size_t oBuf1    = take((size_t)TB * 512 * 2);
  const size_t oH       = take((size_t)(TT + 1) * BB * 512 * 2);
  const size_t oHcur    = take((size_t)BB * 512 * 4);
  const size_t oAbuf    = take((size_t)BB * 512 * 2);
  const size_t oEbuf    = take((size_t)BB * 512 * 2);
  const size_t oGH      = take((size_t)BB * 1536 * 4);
  const size_t oGX      = take((size_t)TB * 1536 * 2);   // fp16 gxpx
  const size_t oSync    = take(16384);

  auto W = [&](size_t off) { return (u16*)(ws + off); };
  u16* BUF0 = W(oBuf0);
  u16* BUF1 = W(oBuf1);
  u16* Hbuf = W(oH);
  float* h_cur = (float*)(ws + oHcur);
  f16* GX16 = (f16*)(ws + oGX);
  unsigned* sync = (unsigned*)(ws + oSync);

  // --- weight cast+transpose (one kernel, 18 segments) ---
  CastArgs ca;
  int si = 0;
  auto seg = [&](const float* src, u16* dst, int R, int C) { ca.seg[si++] = {src, dst, R, C}; };
  seg(in(2), W(oPhiXW1), 128, 512);
  seg(in(4), W(oPhiXW2), 512, 512);
  seg(in(8), W(oEncW1px), 512, 512);
  seg(in(8) + 512 * 512, W(oEncW1h), 512, 512);
  seg(in(10), W(oEncW2), 512, 512);
  seg(in(12), W(oEms), 512, 64);
  seg(in(14), W(oEms) + 64 * 512, 512, 64);
  seg(in(6), W(oPhiZ), 64, 512);
  seg(in(16), W(oPriorW), 512, 512);
  seg(in(18), W(oPriorMs), 512, 64);
  seg(in(20), W(oPriorMs) + 64 * 512, 512, 64);
  seg(in(22), W(oDecW1pz), 512, 512);
  seg(in(22) + 512 * 512, W(oDecW1h), 512, 512);
  seg(in(24), W(oDecW2), 512, 512);
  seg(in(26), W(oDecLog), 512, 256);
  seg(in(28), W(oGruIhPx), 512, 1536);
  seg(in(28) + 512 * 1536, W(oGruIhPz), 512, 1536);
  seg(in(30), W(oGruHh), 512, 1536);
  hipLaunchKernelGGL(cast_all, dim3(18816), dim3(256), 0, stream, ca);
  hipLaunchKernelGGL(init_k, dim3(512), dim3(256), 0, stream, h_cur, Hbuf, sync);

  auto gemm = [&](const void* A1, int lda1, int K1, int a1f32, const u16* Bt1,
                  const u16* A2, int lda2, int K2, const u16* Bt2,
                  const float* bias, u16* outB, float* outF, f16* outH,
                  int ldc, int N, int act) {
    GB g;
    g.A1 = A1; g.lda1 = lda1; g.K1 = K1; g.a1f32 = a1f32; g.Bt1 = Bt1;
    g.A2 = A2; g.lda2 = lda2; g.K2 = K2; g.Bt2 = Bt2;
    g.bias = bias; g.outB = outB; g.outF = outF; g.outH = outH; g.ldc = ldc;
    g.tilesN = N / 64; g.act = act;
    hipLaunchKernelGGL(gemm_bt, dim3((TB / 64) * (N / 64)), dim3(256), 0, stream, g);
  };

  // --- pre-pass ---
  // PX1 = relu(x @ phi_x_w1 + b1)          -> BUF0
  gemm(in(0), 128, 128, 1, W(oPhiXW1), nullptr, 0, 0, nullptr, in(3), BUF0, nullptr, nullptr, 512, 512, 1);
  // PX  = relu(PX1 @ phi_x_w2 + b2)        -> BUF1
  gemm(BUF0, 512, 512, 0, W(oPhiXW2), nullptr, 0, 0, nullptr, in(5), BUF1, nullptr, nullptr, 512, 512, 1);
  // PRE_ENC = PX @ enc_w1[:512] + enc_b1   -> BUF0
  gemm(BUF1, 512, 512, 0, W(oEncW1px), nullptr, 0, 0, nullptr, in(9), BUF0, nullptr, nullptr, 512, 512, 0);
  // GX16 = PX @ gru_w_ih[:512] + b_ih      -> fp16
  gemm(BUF1, 512, 512, 0, W(oGruIhPx), nullptr, 0, 0, nullptr, in(29), nullptr, nullptr, GX16, 1536, 1536, 0);

  // --- sequential scan (32 WGs, LDS weights, fence-free coherent traffic) ---
  SC sc;
  sc.pre_enc = BUF0; sc.pz_out = BUF0;
  sc.H = Hbuf; sc.h_cur = h_cur;
  sc.Abuf = W(oAbuf); sc.Ebuf = W(oEbuf);
  sc.GH = (float*)(ws + oGH); sc.gx = GX16;
  sc.enc_w1_h_t = W(oEncW1h); sc.enc_w2_t = W(oEncW2); sc.ems_t = W(oEms);
  sc.phi_z_t = W(oPhiZ); sc.gru_hh_t = W(oGruHh); sc.gru_ih_pz_t = W(oGruIhPz);
  sc.enc_b2 = in(11); sc.enc_mean_b = in(13); sc.enc_std_b = in(15);
  sc.phi_z_b = in(7); sc.gru_b_hh = in(31);
  sc.eps = in(1); sc.out = out;
  sc.flags = sync; sc.gen = sync + 2048;
  hipLaunchKernelGGL(scan_k, dim3(NWG), dim3(256), 0, stream, sc);

  // --- post-pass (batched over all T; BUF0 now holds PZ written by scan) ---
  // PR = relu(Hprev @ prior_w + b)         -> BUF1
  gemm(Hbuf, 512, 512, 0, W(oPriorW), nullptr, 0, 0, nullptr, in(17), BUF1, nullptr, nullptr, 512, 512, 1);
  // pm/ps/kld                              -> d_out
  hipLaunchKernelGGL(pms_kld, dim3(TB / 64), dim3(256), 0, stream,
                     BUF1, W(oPriorMs), in(19), in(21), out);
  // DH1 = relu(PZ@dec_w1[:512] + Hprev@dec_w1[512:] + b1) -> BUF1
  gemm(BUF0, 512, 512, 0, W(oDecW1pz), Hbuf, 512, 512, W(oDecW1h), in(23), BUF1, nullptr, nullptr, 512, 512, 1);
  // D = relu(DH1 @ dec_w2 + b2)            -> BUF0
  gemm(BUF1, 512, 512, 0, W(oDecW2), nullptr, 0, 0, nullptr, in(25), BUF0, nullptr, nullptr, 512, 512, 1);
  // logits = D @ dec_logits + b            -> d_out fp32
  gemm(BUF0, 512, 512, 0, W(oDecLog), nullptr, 0, 0, nullptr, in(27), nullptr, out + OFF_LOGITS, nullptr, 256, 256, 0);
}

// Round 4
// 18519.096 us; speedup vs baseline: 1.8874x; 1.8874x over previous
//
#include <hip/hip_runtime.h>
#include <math.h>

// ---------------------------------------------------------------------------
// VRNN on MI355X — round 4.
// Rounds 0/2/3 proved: ANY software grid barrier in a persistent kernel costs
// ~30µs/phase on this chip (invariant across 64/32 WGs, fenced or fence-free).
// Round 4 deletes the persistent kernel: the 3-deep per-step dependency chain
// is synchronized by the command processor instead — 3 small kernels per step
// (600 dispatches in the captured graph), each with a full-width grid:
//   ag_k  [128 WG]: A = relu(pre_enc[t] + h@enc_w1_h);  GH = h@gru_hh + b_hh
//   et_k  [ 16 WG]: E = relu(A@enc_w2+b2) -> ems -> z(out) -> pz  (row-local)
//   gru_k [ 32 WG]: gx = gx16 + pz@gru_ih_pz (3-gate tiles); GRU -> h, H[t+1]
// Pre-pass: PX=phi_x(x); PRE_ENC; GX16=PX@gru_w_ih[:512]+b_ih (fp16).
// Post-pass: prior chain (+kld), decoder chain (pz written by et_k into BUF0).
// All GEMMs: bf16 MFMA 16x16x32, fp32 accum, weights pre-transposed to [N][K].
// ---------------------------------------------------------------------------

#define TT 200
#define BB 256
#define HD 512
#define TB (TT*BB)   // 51200

typedef unsigned short u16;
typedef _Float16 f16;
typedef __attribute__((ext_vector_type(8))) short bf16x8;
typedef __attribute__((ext_vector_type(4))) float f32x4;

// output layout (fp32, concatenated flat): z, logits, em, es, pm, ps, kld
constexpr size_t OFF_Z      = 0;
constexpr size_t OFF_LOGITS = 3276800;
constexpr size_t OFF_EM     = 16384000;
constexpr size_t OFF_ES     = 19660800;
constexpr size_t OFF_PM     = 22937600;
constexpr size_t OFF_PS     = 26214400;
constexpr size_t OFF_KLD    = 29491200;

__device__ __forceinline__ u16 f2bf(float f) {
  union { float f; unsigned u; } v; v.f = f;
  return (u16)((v.u + 0x7fffu + ((v.u >> 16) & 1u)) >> 16);  // RNE
}
__device__ __forceinline__ float bf2f(u16 b) {
  union { unsigned u; float f; } v; v.u = ((unsigned)b) << 16; return v.f;
}
__device__ __forceinline__ float sp_(float x) { return (x > 15.f) ? x : log1pf(expf(x)); }
__device__ __forceinline__ float sigm_(float x) { return 1.f / (1.f + __expf(-x)); }
__device__ __forceinline__ float tanh_(float x) { return 1.f - 2.f / (1.f + __expf(2.f * x)); }

#define MFMA(a,b,c) __builtin_amdgcn_mfma_f32_16x16x32_bf16((a),(b),(c),0,0,0)

// LDS XOR-swizzle for [row][512] bf16 tiles (row stride 1024B).
#define SWZ(row, cb)  (((row) << 10) + ((cb) ^ (((row) & 7) << 4)))
// [16][64] bf16 tile, row stride 128B
#define SWZZ(row, cb) (((row) << 7)  + ((cb) ^ (((row) & 7) << 4)))

// ---------------------------------------------------------------------------
// weight cast+transpose: dst[c*R + r] = bf16(src[r*C + c])   (dst is [C][R])
// ---------------------------------------------------------------------------
#define NSEG 18
struct CastSeg { const float* src; u16* dst; int R; int C; };
struct CastArgs { CastSeg seg[NSEG]; };

__global__ __launch_bounds__(256) void cast_all(CastArgs a) {
  int idx = blockIdx.x * 256 + threadIdx.x;
  #pragma unroll 1
  for (int s = 0; s < NSEG; s++) {
    const int R = a.seg[s].R, C = a.seg[s].C;
    const int sz = R * C;
    if (idx < sz) {
      const int r = idx / C, c = idx - r * C;
      a.seg[s].dst[(size_t)c * R + r] = f2bf(a.seg[s].src[idx]);
      return;
    }
    idx -= sz;
  }
}

__global__ __launch_bounds__(256) void init_k(float* h_cur, u16* H0) {
  const int i = blockIdx.x * 256 + threadIdx.x;
  if (i < BB * HD) { h_cur[i] = 0.f; H0[i] = 0; }
}

// ---------------------------------------------------------------------------
// generic batched GEMM:  out = act( A1@Bt1^T [+ A2@Bt2^T] + bias )
// ---------------------------------------------------------------------------
struct GB {
  const void* A1; int lda1, K1, a1f32;
  const u16* Bt1;
  const u16* A2; int lda2, K2;
  const u16* Bt2;
  const float* bias;
  u16* outB; float* outF; f16* outH; int ldc;
  int tilesN; int act;   // act: 0 none, 1 relu
};

__device__ __forceinline__ bf16x8 load_a8(const void* A, int f32, size_t row, int lda, int k) {
  if (!f32) return *(const bf16x8*)((const u16*)A + row * (size_t)lda + k);
  const float* p = (const float*)A + row * (size_t)lda + k;
  f32x4 x0 = *(const f32x4*)p;
  f32x4 x1 = *(const f32x4*)(p + 4);
  bf16x8 r;
  r[0]=(short)f2bf(x0[0]); r[1]=(short)f2bf(x0[1]); r[2]=(short)f2bf(x0[2]); r[3]=(short)f2bf(x0[3]);
  r[4]=(short)f2bf(x1[0]); r[5]=(short)f2bf(x1[1]); r[6]=(short)f2bf(x1[2]); r[7]=(short)f2bf(x1[3]);
  return r;
}

__global__ __launch_bounds__(256) void gemm_bt(GB g) {
  const int tn = blockIdx.x % g.tilesN, tm = blockIdx.x / g.tilesN;
  const int m0 = tm * 64, n0 = tn * 64;
  const int v = threadIdx.x >> 6, l = threadIdx.x & 63, lm = l & 15, q = l >> 4;
  const size_t rowA = m0 + v * 16 + lm;
  f32x4 acc[4] = {};
  for (int k0 = 0; k0 < g.K1; k0 += 32) {
    bf16x8 a = load_a8(g.A1, g.a1f32, rowA, g.lda1, k0 + q * 8);
    #pragma unroll
    for (int c = 0; c < 4; c++) {
      bf16x8 b = *(const bf16x8*)(g.Bt1 + (size_t)(n0 + c * 16 + lm) * g.K1 + k0 + q * 8);
      acc[c] = MFMA(a, b, acc[c]);
    }
  }
  if (g.A2) {
    for (int k0 = 0; k0 < g.K2; k0 += 32) {
      bf16x8 a = *(const bf16x8*)(g.A2 + rowA * (size_t)g.lda2 + k0 + q * 8);
      #pragma unroll
      for (int c = 0; c < 4; c++) {
        bf16x8 b = *(const bf16x8*)(g.Bt2 + (size_t)(n0 + c * 16 + lm) * g.K2 + k0 + q * 8);
        acc[c] = MFMA(a, b, acc[c]);
      }
    }
  }
  #pragma unroll
  for (int c = 0; c < 4; c++) {
    const int col = n0 + c * 16 + lm;
    const float bs = g.bias ? g.bias[col] : 0.f;
    #pragma unroll
    for (int r = 0; r < 4; r++) {
      const size_t row = (size_t)m0 + v * 16 + q * 4 + r;
      float x = acc[c][r] + bs;
      if (g.act == 1) x = fmaxf(x, 0.f);
      if (g.outB) g.outB[row * g.ldc + col] = f2bf(x);
      if (g.outF) g.outF[row * g.ldc + col] = x;
      if (g.outH) g.outH[row * g.ldc + col] = (f16)x;
    }
  }
}

// ---------------------------------------------------------------------------
// prior mean/std heads + kld, fused (post-pass).
// ---------------------------------------------------------------------------
__global__ __launch_bounds__(256) void pms_kld(const u16* PR, const u16* pms_t,
                                               const float* pmb, const float* psb,
                                               float* out) {
  const int m0 = blockIdx.x * 64;
  const int v = threadIdx.x >> 6, l = threadIdx.x & 63, lm = l & 15, q = l >> 4;
  const size_t rowA = m0 + v * 16 + lm;
  f32x4 acc[8] = {};
  for (int k0 = 0; k0 < 512; k0 += 32) {
    bf16x8 a = *(const bf16x8*)(PR + rowA * 512 + k0 + q * 8);
    #pragma unroll
    for (int c = 0; c < 8; c++) {
      bf16x8 b = *(const bf16x8*)(pms_t + (size_t)(c * 16 + lm) * 512 + k0 + q * 8);
      acc[c] = MFMA(a, b, acc[c]);
    }
  }
  #pragma unroll
  for (int c = 0; c < 4; c++) {
    const int colz = c * 16 + lm;
    #pragma unroll
    for (int r = 0; r < 4; r++) {
      const size_t row = (size_t)m0 + v * 16 + q * 4 + r;
      const float pm = acc[c][r] + pmb[colz];
      const float ps = sp_(acc[c + 4][r] + psb[colz]);
      const size_t oi = row * 64 + colz;
      const float em = out[OFF_EM + oi], es = out[OFF_ES + oi];
      const float d = em - pm;
      const float kld = 0.5f * (2.f * logf(ps) - 2.f * logf(es)
                                + (es * es + d * d) / (ps * ps) - 1.f);
      out[OFF_PM + oi] = pm;
      out[OFF_PS + oi] = ps;
      out[OFF_KLD + oi] = kld;
    }
  }
}

// ---------------------------------------------------------------------------
// per-step kernels (CP-synchronized; no in-kernel grid barriers)
// ---------------------------------------------------------------------------
struct SP {
  const u16 *pre_enc;   // BUF0 [TT][256][512] bf16 (slice t read by ag_k)
  u16 *pzbuf;           // == BUF0 (slice t overwritten with pz by et_k)
  u16 *H;               // [(TT+1)][256][512] bf16; H[t] = h entering step t
  float *h_cur;         // [256][512] fp32 carry
  u16 *Abuf;            // [256][512] bf16 step scratch
  float *GH;            // [256][1536] fp32 step scratch (h@gru_hh + b_hh)
  const f16 *gx;        // [TB][1536] fp16: px@gru_w_ih[:512] + b_ih
  const u16 *enc_w1_h_t, *enc_w2_t, *ems_t, *phi_z_t, *gru_hh_t, *gru_ih_pz_t;
  const float *enc_b2, *enc_mean_b, *enc_std_b, *phi_z_b, *gru_b_hh;
  const float *eps;
  float *out;
};

// K1: 128 WGs = 4 m-tiles x 32 n-tiles (n<8 -> A cols, n>=8 -> GH gate cols)
__global__ __launch_bounds__(256) void ag_k(SP s, int t) {
  const int tn = blockIdx.x & 31, tm = blockIdx.x >> 5;
  const int v = threadIdx.x >> 6, l = threadIdx.x & 63, lm = l & 15, q = l >> 4;
  const int m0 = tm * 64;
  const size_t rowA = m0 + v * 16 + lm;
  const u16* Ht = s.H + (size_t)t * (BB * HD);
  const bool isA = (tn < 8);
  const int n0 = isA ? tn * 64 : (tn - 8) * 64;
  const u16* Bt = isA ? s.enc_w1_h_t : s.gru_hh_t;
  f32x4 acc[4] = {};
  for (int k0 = 0; k0 < 512; k0 += 32) {
    bf16x8 a = *(const bf16x8*)(Ht + rowA * 512 + k0 + q * 8);
    #pragma unroll
    for (int c = 0; c < 4; c++) {
      bf16x8 b = *(const bf16x8*)(Bt + (size_t)(n0 + c * 16 + lm) * 512 + k0 + q * 8);
      acc[c] = MFMA(a, b, acc[c]);
    }
  }
  if (isA) {
    const u16* pre = s.pre_enc + (size_t)t * (BB * HD);
    #pragma unroll
    for (int c = 0; c < 4; c++) {
      const int col = n0 + c * 16 + lm;
      #pragma unroll
      for (int r = 0; r < 4; r++) {
        const int row = m0 + v * 16 + q * 4 + r;
        const float x = acc[c][r] + bf2f(pre[(size_t)row * 512 + col]);
        s.Abuf[(size_t)row * 512 + col] = f2bf(fmaxf(x, 0.f));
      }
    }
  } else {
    #pragma unroll
    for (int c = 0; c < 4; c++) {
      const int colg = n0 + c * 16 + lm;
      const float bs = s.gru_b_hh[colg];
      #pragma unroll
      for (int r = 0; r < 4; r++) {
        const int row = m0 + v * 16 + q * 4 + r;
        s.GH[(size_t)row * 1536 + colg] = acc[c][r] + bs;
      }
    }
  }
}

// K2+K3: 16 WGs, each rows r0=16w..+16: E(LDS) -> ems -> z(out) -> pz(global)
__global__ __launch_bounds__(256) void et_k(SP s, int t) {
  const int w = blockIdx.x;
  const int tid = threadIdx.x;
  const int v = tid >> 6, l = tid & 63, lm = l & 15, q = l >> 4;
  const int r0 = w * 16;
  __shared__ u16 elds[16 * 512];
  __shared__ float emsb[16 * 128];
  __shared__ u16 zb[16 * 64];

  // E = relu(A@enc_w2 + b2); wave v -> cols v*128..+128
  {
    f32x4 acc[8] = {};
    for (int k0 = 0; k0 < 512; k0 += 32) {
      bf16x8 a = *(const bf16x8*)(s.Abuf + (size_t)(r0 + lm) * 512 + k0 + q * 8);
      #pragma unroll
      for (int ct = 0; ct < 8; ct++) {
        bf16x8 b = *(const bf16x8*)(s.enc_w2_t + (size_t)(v * 128 + ct * 16 + lm) * 512 + k0 + q * 8);
        acc[ct] = MFMA(a, b, acc[ct]);
      }
    }
    #pragma unroll
    for (int ct = 0; ct < 8; ct++) {
      const int col = v * 128 + ct * 16 + lm;
      const float bs = s.enc_b2[col];
      #pragma unroll
      for (int r = 0; r < 4; r++) {
        const int row = q * 4 + r;
        *(u16*)((char*)elds + SWZ(row, col * 2)) = f2bf(fmaxf(acc[ct][r] + bs, 0.f));
      }
    }
  }
  __syncthreads();

  // ems: wave v -> cols v*32..+32 (of 128)
  {
    f32x4 e0 = {}, e1 = {};
    const int cb = v * 32;
    for (int k0 = 0; k0 < 512; k0 += 32) {
      bf16x8 a  = *(const bf16x8*)((const char*)elds + SWZ(lm, (k0 + q * 8) * 2));
      bf16x8 b0 = *(const bf16x8*)(s.ems_t + (size_t)(cb + lm) * 512 + k0 + q * 8);
      bf16x8 b1 = *(const bf16x8*)(s.ems_t + (size_t)(cb + 16 + lm) * 512 + k0 + q * 8);
      e0 = MFMA(a, b0, e0);
      e1 = MFMA(a, b1, e1);
    }
    #pragma unroll
    for (int ct = 0; ct < 2; ct++) {
      const int col = cb + ct * 16 + lm;
      const float bs = (col < 64) ? s.enc_mean_b[col] : s.enc_std_b[col - 64];
      const f32x4 ee = ct ? e1 : e0;
      #pragma unroll
      for (int r = 0; r < 4; r++)
        emsb[(q * 4 + r) * 128 + col] = ee[r] + bs;
    }
  }
  __syncthreads();

  // z = eps*sp(es)+em; write z/em/es outputs + zb
  #pragma unroll
  for (int i = 0; i < 4; i++) {
    const int e = tid + i * 256;              // 16 rows x 64 cols
    const int rr = e >> 6, cc = e & 63;
    const float em = emsb[rr * 128 + cc];
    const float es = sp_(emsb[rr * 128 + 64 + cc]);
    const int row = r0 + rr;
    const size_t oi = ((size_t)t * BB + row) * 64 + cc;
    const float z = s.eps[oi] * es + em;
    s.out[OFF_Z + oi]  = z;
    s.out[OFF_EM + oi] = em;
    s.out[OFF_ES + oi] = es;
    *(u16*)((char*)zb + SWZZ(rr, cc * 2)) = f2bf(z);
  }
  __syncthreads();

  // pz = relu(z @ phi_z + b) -> global (BUF0 slice t)
  {
    u16* pzg = s.pzbuf + (size_t)t * (BB * HD);
    #pragma unroll
    for (int ct = 0; ct < 8; ct++) {
      const int cz = v * 128 + ct * 16;
      f32x4 pa = {};
      #pragma unroll
      for (int k0 = 0; k0 < 64; k0 += 32) {
        bf16x8 a = *(const bf16x8*)((const char*)zb + SWZZ(lm, (k0 + q * 8) * 2));
        bf16x8 b = *(const bf16x8*)(s.phi_z_t + (size_t)(cz + lm) * 64 + k0 + q * 8);
        pa = MFMA(a, b, pa);
      }
      const int col = cz + lm;
      const float bs = s.phi_z_b[col];
      #pragma unroll
      for (int r = 0; r < 4; r++) {
        const int row = r0 + q * 4 + r;
        pzg[(size_t)row * 512 + col] = f2bf(fmaxf(pa[r] + bs, 0.f));
      }
    }
  }
}

// K4: 32 WGs = 4 m-tiles x 8 j-tiles; 3-gate GEMM + fused GRU elementwise
__global__ __launch_bounds__(256) void gru_k(SP s, int t) {
  const int jt = blockIdx.x & 7, tm = blockIdx.x >> 3;
  const int v = threadIdx.x >> 6, l = threadIdx.x & 63, lm = l & 15, q = l >> 4;
  const int m0 = tm * 64, j0 = jt * 64;
  const size_t rowA = m0 + v * 16 + lm;
  const u16* pz = s.pzbuf + (size_t)t * (BB * HD);
  f32x4 acc[3][4] = {};
  for (int k0 = 0; k0 < 512; k0 += 32) {
    bf16x8 a = *(const bf16x8*)(pz + rowA * 512 + k0 + q * 8);
    #pragma unroll
    for (int g = 0; g < 3; g++) {
      #pragma unroll
      for (int c = 0; c < 4; c++) {
        bf16x8 b = *(const bf16x8*)(s.gru_ih_pz_t
                     + (size_t)(g * 512 + j0 + c * 16 + lm) * 512 + k0 + q * 8);
        acc[g][c] = MFMA(a, b, acc[g][c]);
      }
    }
  }
  const f16* gxt = s.gx + (size_t)t * BB * 1536;
  u16* Hn = s.H + (size_t)(t + 1) * (BB * HD);
  #pragma unroll
  for (int c = 0; c < 4; c++) {
    const int j = j0 + c * 16 + lm;
    #pragma unroll
    for (int r = 0; r < 4; r++) {
      const int row = m0 + v * 16 + q * 4 + r;
      const size_t base = (size_t)row * 1536;
      const float xr = acc[0][c][r] + (float)gxt[base + j];
      const float xz = acc[1][c][r] + (float)gxt[base + 512 + j];
      const float xn = acc[2][c][r] + (float)gxt[base + 1024 + j];
      const float hr = s.GH[base + j];
      const float hz = s.GH[base + 512 + j];
      const float hn = s.GH[base + 1024 + j];
      const float rg = sigm_(xr + hr);
      const float uu = sigm_(xz + hz);
      const float nn = tanh_(xn + rg * hn);
      const float hold = s.h_cur[(size_t)row * 512 + j];
      const float hnew = (1.f - uu) * nn + uu * hold;
      s.h_cur[(size_t)row * 512 + j] = hnew;
      Hn[(size_t)row * 512 + j] = f2bf(hnew);
    }
  }
}

// ---------------------------------------------------------------------------
extern "C" void kernel_launch(void* const* d_in, const int* in_sizes, int n_in,
                              void* d_out, int out_size, void* d_ws, size_t ws_size,
                              hipStream_t stream) {
  (void)in_sizes; (void)n_in; (void)out_size; (void)ws_size;
  char* ws = (char*)d_ws;
  float* out = (float*)d_out;
  auto in = [&](int i) { return (const float*)d_in[i]; };

  size_t o = 0;
  auto take = [&](size_t bytes) { size_t r = o; o += (bytes + 255) & ~(size_t)255; return r; };
  const size_t oPhiXW1  = take(512 * 128 * 2);
  const size_t oPhiXW2  = take(512 * 512 * 2);
  const size_t oEncW1px = take(512 * 512 * 2);
  const size_t oEncW1h  = take(512 * 512 * 2);
  const size_t oEncW2   = take(512 * 512 * 2);
  const size_t oEms     = take(128 * 512 * 2);
  const size_t oPhiZ    = take(512 * 64 * 2);
  const size_t oPriorW  = take(512 * 512 * 2);
  const size_t oPriorMs = take(128 * 512 * 2);
  const size_t oDecW1pz = take(512 * 512 * 2);
  const size_t oDecW1h  = take(512 * 512 * 2);
  const size_t oDecW2   = take(512 * 512 * 2);
  const size_t oDecLog  = take(256 * 512 * 2);
  const size_t oGruIhPx = take((size_t)1536 * 512 * 2);
  const size_t oGruIhPz = take((size_t)1536 * 512 * 2);
  const size_t oGruHh   = take((size_t)1536 * 512 * 2);
  const size_t oBuf0    = take((size_t)TB * 512 * 2);
  const size_t oBuf1    = take((size_t)TB * 512 * 2);
  const size_t oH       = take((size_t)(TT + 1) * BB * 512 * 2);
  const size_t oHcur    = take((size_t)BB * 512 * 4);
  const size_t oAbuf    = take((size_t)BB * 512 * 2);
  const size_t oGH      = take((size_t)BB * 1536 * 4);
  const size_t oGX      = take((size_t)TB * 1536 * 2);   // fp16 gxpx

  auto W = [&](size_t off) { return (u16*)(ws + off); };
  u16* BUF0 = W(oBuf0);
  u16* BUF1 = W(oBuf1);
  u16* Hbuf = W(oH);
  float* h_cur = (float*)(ws + oHcur);
  f16* GX16 = (f16*)(ws + oGX);

  // --- weight cast+transpose (one kernel, 18 segments) ---
  CastArgs ca;
  int si = 0;
  auto seg = [&](const float* src, u16* dst, int R, int C) { ca.seg[si++] = {src, dst, R, C}; };
  seg(in(2), W(oPhiXW1), 128, 512);
  seg(in(4), W(oPhiXW2), 512, 512);
  seg(in(8), W(oEncW1px), 512, 512);
  seg(in(8) + 512 * 512, W(oEncW1h), 512, 512);
  seg(in(10), W(oEncW2), 512, 512);
  seg(in(12), W(oEms), 512, 64);
  seg(in(14), W(oEms) + 64 * 512, 512, 64);
  seg(in(6), W(oPhiZ), 64, 512);
  seg(in(16), W(oPriorW), 512, 512);
  seg(in(18), W(oPriorMs), 512, 64);
  seg(in(20), W(oPriorMs) + 64 * 512, 512, 64);
  seg(in(22), W(oDecW1pz), 512, 512);
  seg(in(22) + 512 * 512, W(oDecW1h), 512, 512);
  seg(in(24), W(oDecW2), 512, 512);
  seg(in(26), W(oDecLog), 512, 256);
  seg(in(28), W(oGruIhPx), 512, 1536);
  seg(in(28) + 512 * 1536, W(oGruIhPz), 512, 1536);
  seg(in(30), W(oGruHh), 512, 1536);
  hipLaunchKernelGGL(cast_all, dim3(18816), dim3(256), 0, stream, ca);
  hipLaunchKernelGGL(init_k, dim3(512), dim3(256), 0, stream, h_cur, Hbuf);

  auto gemm = [&](const void* A1, int lda1, int K1, int a1f32, const u16* Bt1,
                  const u16* A2, int lda2, int K2, const u16* Bt2,
                  const float* bias, u16* outB, float* outF, f16* outH,
                  int ldc, int N, int act) {
    GB g;
    g.A1 = A1; g.lda1 = lda1; g.K1 = K1; g.a1f32 = a1f32; g.Bt1 = Bt1;
    g.A2 = A2; g.lda2 = lda2; g.K2 = K2; g.Bt2 = Bt2;
    g.bias = bias; g.outB = outB; g.outF = outF; g.outH = outH; g.ldc = ldc;
    g.tilesN = N / 64; g.act = act;
    hipLaunchKernelGGL(gemm_bt, dim3((TB / 64) * (N / 64)), dim3(256), 0, stream, g);
  };

  // --- pre-pass ---
  // PX1 = relu(x @ phi_x_w1 + b1)          -> BUF0
  gemm(in(0), 128, 128, 1, W(oPhiXW1), nullptr, 0, 0, nullptr, in(3), BUF0, nullptr, nullptr, 512, 512, 1);
  // PX  = relu(PX1 @ phi_x_w2 + b2)        -> BUF1
  gemm(BUF0, 512, 512, 0, W(oPhiXW2), nullptr, 0, 0, nullptr, in(5), BUF1, nullptr, nullptr, 512, 512, 1);
  // PRE_ENC = PX @ enc_w1[:512] + enc_b1   -> BUF0
  gemm(BUF1, 512, 512, 0, W(oEncW1px), nullptr, 0, 0, nullptr, in(9), BUF0, nullptr, nullptr, 512, 512, 0);
  // GX16 = PX @ gru_w_ih[:512] + b_ih      -> fp16
  gemm(BUF1, 512, 512, 0, W(oGruIhPx), nullptr, 0, 0, nullptr, in(29), nullptr, nullptr, GX16, 1536, 1536, 0);

  // --- sequential scan: 3 CP-synchronized kernels per step ---
  SP sp;
  sp.pre_enc = BUF0; sp.pzbuf = BUF0;
  sp.H = Hbuf; sp.h_cur = h_cur;
  sp.Abuf = W(oAbuf); sp.GH = (float*)(ws + oGH); sp.gx = GX16;
  sp.enc_w1_h_t = W(oEncW1h); sp.enc_w2_t = W(oEncW2); sp.ems_t = W(oEms);
  sp.phi_z_t = W(oPhiZ); sp.gru_hh_t = W(oGruHh); sp.gru_ih_pz_t = W(oGruIhPz);
  sp.enc_b2 = in(11); sp.enc_mean_b = in(13); sp.enc_std_b = in(15);
  sp.phi_z_b = in(7); sp.gru_b_hh = in(31);
  sp.eps = in(1); sp.out = out;
  for (int t = 0; t < TT; t++) {
    hipLaunchKernelGGL(ag_k,  dim3(128), dim3(256), 0, stream, sp, t);
    hipLaunchKernelGGL(et_k,  dim3(16),  dim3(256), 0, stream, sp, t);
    hipLaunchKernelGGL(gru_k, dim3(32),  dim3(256), 0, stream, sp, t);
  }

  // --- post-pass (batched over all T; BUF0 now holds PZ written by et_k) ---
  // PR = relu(Hprev @ prior_w + b)         -> BUF1
  gemm(Hbuf, 512, 512, 0, W(oPriorW), nullptr, 0, 0, nullptr, in(17), BUF1, nullptr, nullptr, 512, 512, 1);
  // pm/ps/kld                              -> d_out
  hipLaunchKernelGGL(pms_kld, dim3(TB / 64), dim3(256), 0, stream,
                     BUF1, W(oPriorMs), in(19), in(21), out);
  // DH1 = relu(PZ@dec_w1[:512] + Hprev@dec_w1[512:] + b1) -> BUF1
  gemm(BUF0, 512, 512, 0, W(oDecW1pz), Hbuf, 512, 512, W(oDecW1h), in(23), BUF1, nullptr, nullptr, 512, 512, 1);
  // D = relu(DH1 @ dec_w2 + b2)            -> BUF0
  gemm(BUF1, 512, 512, 0, W(oDecW2), nullptr, 0, 0, nullptr, in(25), BUF0, nullptr, nullptr, 512, 512, 1);
  // logits = D @ dec_logits + b            -> d_out fp32
  gemm(BUF0, 512, 512, 0, W(oDecLog), nullptr, 0, 0, nullptr, in(27), nullptr, out + OFF_LOGITS, nullptr, 256, 256, 0);
}